// Round 7
// baseline (2365.368 us; speedup 1.0000x reference)
//
#include <hip/hip_runtime.h>

// Round 7: XCD-local persistent GRU, no K-split (4 row-groups x 2 col-halves
// per block -> zero cross-wave reduction), flag-line barrier (no atomics on
// the hot path), deeper prefetch. 8 groups (physical XCDs) x 32 blocks x 512.

typedef unsigned short ushort_t;
typedef __bf16 bf16x8 __attribute__((ext_vector_type(8)));
typedef float f32x4 __attribute__((ext_vector_type(4)));
typedef unsigned int u32x4 __attribute__((ext_vector_type(4)));

#define MFMA(a, b, c) __builtin_amdgcn_mfma_f32_16x16x32_bf16(a, b, c, 0, 0, 0)
#define AL(p) __hip_atomic_load(p, __ATOMIC_RELAXED, __HIP_MEMORY_SCOPE_AGENT)
#define AS(p, v) __hip_atomic_store(p, v, __ATOMIC_RELAXED, __HIP_MEMORY_SCOPE_AGENT)

static __device__ __forceinline__ ushort_t f2bf(float f) {
  union { float f; unsigned u; } x; x.f = f;
  unsigned r = x.u + 0x7fffu + ((x.u >> 16) & 1u);
  return (ushort_t)(r >> 16);
}
static __device__ __forceinline__ float sigmf(float x) { return 1.f / (1.f + __expf(-x)); }
static __device__ __forceinline__ float tanhf_(float x) { return 1.f - 2.f / (__expf(2.f * x) + 1.f); }

static __device__ __forceinline__ __amdgpu_buffer_rsrc_t mkrsrc(const void* p) {
  return __builtin_amdgcn_make_buffer_rsrc(const_cast<void*>(p), (short)0, -1, 0x00020000);
}
// aux=1 -> sc0: bypass vL1, read XCD-local L2 (cross-block coherent).
#if __has_builtin(__builtin_amdgcn_raw_buffer_load_b128)
static __device__ __forceinline__ bf16x8 ldb(__amdgpu_buffer_rsrc_t r, int voff) {
  u32x4 v = __builtin_amdgcn_raw_buffer_load_b128(r, voff, 0, 1);
  union { u32x4 u; bf16x8 b; } x; x.u = v; return x.b;
}
#else
static __device__ __forceinline__ bf16x8 ldb(__amdgpu_buffer_rsrc_t r, int voff) {
  union { unsigned u[4]; bf16x8 b; } x;
  x.u[0] = __builtin_amdgcn_raw_buffer_load_b32(r, voff, 0, 1);
  x.u[1] = __builtin_amdgcn_raw_buffer_load_b32(r, voff + 4, 0, 1);
  x.u[2] = __builtin_amdgcn_raw_buffer_load_b32(r, voff + 8, 0, 1);
  x.u[3] = __builtin_amdgcn_raw_buffer_load_b32(r, voff + 12, 0, 1);
  return x.b;
}
#endif

__global__ __launch_bounds__(512, 2)
void seq2seq_xcd(const float* __restrict__ enc, const float* __restrict__ dec,
                 const float* __restrict__ Wih, const float* __restrict__ Whh,
                 const float* __restrict__ b_ih, const float* __restrict__ b_hh,
                 const float* __restrict__ fcw, const float* __restrict__ fcb,
                 float* __restrict__ outp,
                 ushort_t* __restrict__ xg, ushort_t* __restrict__ hA,
                 ushort_t* __restrict__ innA, ushort_t* __restrict__ nG,
                 ushort_t* __restrict__ fcG, unsigned* cnt) {
  __shared__ ushort_t WrzL[65536];  // [kt32][gate2(r,z)][jf2][512]  128 KB
  __shared__ ushort_t WiL[6144];    // [kt2][gate3][jf2][512]         12 KB
  __shared__ float scr[1024];       // fcdo pair-reduction              4 KB
  __shared__ unsigned sgs;

  const int tid = threadIdx.x;
  const int w = tid >> 6, l = tid & 63;
  const int fr = l & 15, fq4 = l >> 4;

  // ---- claim XCD-local slot ----
  if (tid == 0) {
    unsigned x;
    asm volatile("s_getreg_b32 %0, hwreg(HW_REG_XCC_ID, 0, 8)" : "=s"(x));
    x &= 7u;
    unsigned s = atomicAdd(&cnt[x * 64], 1u);
    sgs = (x << 8) | s;
  }
  __syncthreads();
  const int g = sgs >> 8, slot = sgs & 255;
  const bool isFC = (slot >= 24);

  unsigned* aflag = cnt + g * 64;                         // dwords 1..31 = slots
  unsigned* rflag = cnt + 512 + (g * 32 + slot) * 32;     // private release line
  auto fcpp = [&](int td) { return cnt + 9000 + (g * 25 + td) * 32; };

  ushort_t* hbase = hA + (size_t)g * 262144;
  auto hb = [&](int i) { return hbase + (size_t)i * 131072; };
  ushort_t* xgg = xg + (size_t)g * 49 * 8192;
  auto inng = [&](int i) { return innA + (size_t)(g * 2 + i) * 8192; };
  ushort_t* nGp = nG + (size_t)(g * 32 + slot) * 32768;
  ushort_t* fcGg = fcG + (size_t)g * 65536;

  // ---- init: coalesced Whh -> WrzL (LDS) and nG (global), frag order ----
  {
    const int q = tid & 127, cc = tid >> 7;  // q sweeps K (8 floats), 4 cols/pass
    const int kt = q >> 2, lnp = (q & 3) * 16;
#pragma unroll
    for (int p = cc; p < 64; p += 4) {  // p = gt*32 + c  (gates r,z)
      int gt = p >> 5, c = p & 31;
      const float* src = Whh + (size_t)(gt * 1024 + slot * 32 + c) * 1024 + q * 8;
      ushort_t* dst = WrzL + kt * 2048 + gt * 1024 + (c >> 4) * 512 + ((c & 15) + lnp) * 8;
#pragma unroll
      for (int j = 0; j < 8; ++j) dst[j] = f2bf(src[j]);
    }
#pragma unroll
    for (int p = cc; p < 32; p += 4) {  // n-gate -> block-private global
      const float* src = Whh + (size_t)(2048 + slot * 32 + p) * 1024 + q * 8;
      ushort_t* dst = nGp + kt * 1024 + (p >> 4) * 512 + ((p & 15) + lnp) * 8;
#pragma unroll
      for (int j = 0; j < 8; ++j) dst[j] = f2bf(src[j]);
    }
  }
  for (int i = tid; i < 6144; i += 512) {  // WiL [kt][gt][jf][512]
    int j = i & 7, ln = (i >> 3) & 63, jf = (i >> 9) & 1, rem = i >> 10;
    int gt = rem % 3, kt = rem / 3;
    int col = gt * 1024 + slot * 32 + jf * 16 + (ln & 15);
    int k = kt * 32 + (ln >> 4) * 8 + j;
    WiL[i] = (k < 55) ? f2bf(Wih[(size_t)col * 55 + k]) : (ushort_t)0;
  }
#pragma unroll
  for (int rep = 0; rep < 2; ++rep) {  // x_enc: t = slot, slot+32
    int t = slot + rep * 32;
    if (t < 49) {
      ushort_t* xp = xgg + (size_t)t * 8192;
      for (int i = tid; i < 8192; i += 512) {
        int sub = i & 7, row = (i >> 3) & 127, kc = i >> 10;
        int c = kc * 8 + sub;
        xp[i] = (c < 55) ? f2bf(enc[((size_t)(g * 128 + row) * 50 + t) * 55 + c]) : (ushort_t)0;
      }
    }
  }
  if (slot < 4) {  // inn(0) = dec[:,0,:]
    ushort_t* ip = inng(0);
    for (int i = slot * 2048 + tid; i < (slot + 1) * 2048; i += 512) {
      int sub = i & 7, row = (i >> 3) & 127, kc = i >> 10;
      int c = kc * 8 + sub;
      ip[i] = (c < 55) ? f2bf(dec[(size_t)(g * 128 + row) * 1375 + c]) : (ushort_t)0;
    }
  }
  if (isFC) {  // fcG [kt32][jf4][512], group-shared
    for (int i = (slot - 24) * 8192 + tid; i < (slot - 23) * 8192; i += 512) {
      int j = i & 7, ln = (i >> 3) & 63, jf = (i >> 9) & 3, kt = i >> 11;
      int c = jf * 16 + (ln & 15);
      int k = kt * 32 + (ln >> 4) * 8 + j;
      fcG[(size_t)g * 65536 + i] = (c < 55) ? f2bf(fcw[(size_t)c * 1024 + k]) : (ushort_t)0;
    }
  }

  // ---- per-wave constants (wave = 32 rows x 16 cols x 3 gates) ----
  const int jfW = w >> 2;           // col half
  const int R = (w & 3) * 32;       // row base
  const int colW = slot * 32 + jfW * 16 + fr;
  const float brz = b_ih[colW] + b_hh[colW];
  const float bzz = b_ih[1024 + colW] + b_hh[1024 + colW];
  const float bin = b_ih[2048 + colW];
  const float bhn = b_hh[2048 + colW];
  const int Rfc = (slot - 24) * 16;
  const int colF = (w & 3) * 16 + fr;
  float fcbF = 0.f, inp[4] = {0.f, 0.f, 0.f, 0.f};
  if (isFC && w < 4) {
    fcbF = (colF < 55) ? fcb[colF] : 0.f;
#pragma unroll
    for (int v = 0; v < 4; ++v)
      inp[v] = (colF < 55) ? dec[(size_t)(g * 128 + Rfc + fq4 * 4 + v) * 1375 + colF] : 0.f;
  }
  f32x4 hreg[2] = {{0.f, 0.f, 0.f, 0.f}, {0.f, 0.f, 0.f, 0.f}};

  // ---- flag-line barrier (group = one XCD) ----
  auto arrive = [&](unsigned k) {
    __syncthreads();  // drains vmcnt: h stores complete at shared L2
    if (slot == 0) {
      if (w == 0) {
        for (;;) {
          unsigned v = (l >= 1 && l < 32) ? AL(aflag + l) : k;
          if (__ballot(v >= k) == ~0ull) break;
          __builtin_amdgcn_s_sleep(1);
        }
        if (l >= 1 && l < 32) AS(cnt + 512 + (g * 32 + l) * 32, k);
      }
    } else if (tid == 0) {
      AS(aflag + slot, k);
    }
  };
  auto wait_rel = [&](unsigned k) {
    if (slot != 0) {
      if (tid == 0) {
        while (AL(rflag) < k) __builtin_amdgcn_s_sleep(1);
      }
    }
    __syncthreads();
    __builtin_amdgcn_fence(__ATOMIC_ACQUIRE, "agent");
  };
  auto fc_arrive = [&](int td) {
    __syncthreads();
    if (tid == 0) atomicAdd(fcpp(td), 1u);
  };
  auto fc_wait = [&](int td) {
    __syncthreads();
    if (tid == 0) {
      while (AL(fcpp(td)) < 8u) __builtin_amdgcn_s_sleep(1);
    }
    __syncthreads();
    __builtin_amdgcn_fence(__ATOMIC_ACQUIRE, "agent");
  };

  f32x4 aR[2], aZ[2], aNH[2], aNX[2];

  auto xpart = [&](const ushort_t* xp) {
    __amdgpu_buffer_rsrc_t rx = mkrsrc(xp);
#pragma unroll
    for (int kt = 0; kt < 2; ++kt) {
      bf16x8 a0 = ldb(rx, ((kt * 4 + fq4) * 128 + R + fr) * 16);
      bf16x8 a1 = ldb(rx, ((kt * 4 + fq4) * 128 + R + 16 + fr) * 16);
      const ushort_t* bl = WiL + kt * 3072 + jfW * 512 + l * 8;
      bf16x8 br = *(const bf16x8*)(bl);
      bf16x8 bz = *(const bf16x8*)(bl + 1024);
      bf16x8 bn = *(const bf16x8*)(bl + 2048);
      aR[0] = MFMA(a0, br, aR[0]);  aR[1] = MFMA(a1, br, aR[1]);
      aZ[0] = MFMA(a0, bz, aZ[0]);  aZ[1] = MFMA(a1, bz, aZ[1]);
      aNX[0] = MFMA(a0, bn, aNX[0]); aNX[1] = MFMA(a1, bn, aNX[1]);
    }
  };

  auto hpart = [&](const ushort_t* hbp) {  // full K per wave, pipelined
    __amdgpu_buffer_rsrc_t rb = mkrsrc(hbp);
    bf16x8 A0[4], A1[4], BN[2];
#pragma unroll
    for (int i = 0; i < 4; ++i) {
      A0[i] = ldb(rb, ((i * 4 + fq4) * 128 + R + fr) * 16);
      A1[i] = ldb(rb, ((i * 4 + fq4) * 128 + R + 16 + fr) * 16);
    }
    const ushort_t* nbase = nGp + jfW * 512 + l * 8;
    BN[0] = *(const bf16x8*)(nbase);
    BN[1] = *(const bf16x8*)(nbase + 1024);
    const ushort_t* wbase = WrzL + jfW * 512 + l * 8;
    bf16x8 BR = *(const bf16x8*)(wbase);
    bf16x8 BZ = *(const bf16x8*)(wbase + 1024);
#pragma unroll
    for (int kt = 0; kt < 32; ++kt) {
      bf16x8 a0 = A0[kt & 3], a1 = A1[kt & 3], bn = BN[kt & 1], br = BR, bz = BZ;
      if (kt < 28) {
        A0[kt & 3] = ldb(rb, (((kt + 4) * 4 + fq4) * 128 + R + fr) * 16);
        A1[kt & 3] = ldb(rb, (((kt + 4) * 4 + fq4) * 128 + R + 16 + fr) * 16);
      }
      if (kt < 30) BN[kt & 1] = *(const bf16x8*)(nbase + (kt + 2) * 1024);
      if (kt < 31) {
        BR = *(const bf16x8*)(wbase + (kt + 1) * 2048);
        BZ = *(const bf16x8*)(wbase + (kt + 1) * 2048 + 1024);
      }
      aR[0] = MFMA(a0, br, aR[0]);   aR[1] = MFMA(a1, br, aR[1]);
      aZ[0] = MFMA(a0, bz, aZ[0]);   aZ[1] = MFMA(a1, bz, aZ[1]);
      aNH[0] = MFMA(a0, bn, aNH[0]); aNH[1] = MFMA(a1, bn, aNH[1]);
    }
  };

  auto fcdo = [&](const ushort_t* hbp, int td, bool wr) {
    __amdgpu_buffer_rsrc_t rb = mkrsrc(hbp);
    const int kh = w >> 2, jfF = w & 3;
    f32x4 fa = (f32x4){0.f, 0.f, 0.f, 0.f};
    bf16x8 Af[4];
#pragma unroll
    for (int i = 0; i < 4; ++i)
      Af[i] = ldb(rb, (((kh * 16 + i) * 4 + fq4) * 128 + Rfc + fr) * 16);
    const ushort_t* fb = fcGg + jfF * 512 + l * 8;
#pragma unroll
    for (int i = 0; i < 16; ++i) {
      int kt = kh * 16 + i;
      bf16x8 a = Af[i & 3];
      if (i < 12) Af[i & 3] = ldb(rb, (((kt + 4) * 4 + fq4) * 128 + Rfc + fr) * 16);
      fa = MFMA(a, *(const bf16x8*)(fb + kt * 2048), fa);
    }
    if (w >= 4) {
#pragma unroll
      for (int v = 0; v < 4; ++v) scr[v * 256 + (w - 4) * 64 + l] = fa[v];
    }
    __syncthreads();
    if (w < 4) {
#pragma unroll
      for (int v = 0; v < 4; ++v) fa[v] += scr[v * 256 + w * 64 + l];
      const int kq = colF >> 3, sub = colF & 7;
      ushort_t* innW = inng((td + 1) & 1);
#pragma unroll
      for (int v = 0; v < 4; ++v) {
        int row = Rfc + fq4 * 4 + v;
        float o = fa[v] + inp[v] + fcbF;
        inp[v] = o;
        if (wr) innW[(kq * 128 + row) * 8 + sub] = f2bf(o);
        if (colF < 55) outp[(size_t)(g * 128 + row) * 1375 + td * 55 + colF] = o;
      }
    }
    __syncthreads();
  };

  arrive(1);
  wait_rel(1);

  for (int t = 0; t < 74; ++t) {
#pragma unroll
    for (int i = 0; i < 2; ++i) {
      aR[i] = (f32x4){0.f, 0.f, 0.f, 0.f};
      aZ[i] = (f32x4){0.f, 0.f, 0.f, 0.f};
      aNH[i] = (f32x4){0.f, 0.f, 0.f, 0.f};
      aNX[i] = (f32x4){0.f, 0.f, 0.f, 0.f};
    }

    if (t <= 49) xpart(t <= 48 ? xgg + (size_t)t * 8192 : inng(0));
    if (t > 0) wait_rel(t + 1);
    if (t >= 50 && isFC) { fcdo(hb(t & 1), t - 50, true); fc_arrive(t - 50); }
    if (t > 0) hpart(hb(t & 1));
    if (t >= 50) { fc_wait(t - 50); xpart(inng((t - 49) & 1)); }

    {  // epilogue: gates, fp32 carry, publish bf16 h(t+1)
      ushort_t* hn = hb((t + 1) & 1);
      const int kc = colW >> 3, sub = colW & 7;
#pragma unroll
      for (int mi = 0; mi < 2; ++mi)
#pragma unroll
        for (int v = 0; v < 4; ++v) {
          float rr = sigmf(aR[mi][v] + brz);
          float zz = sigmf(aZ[mi][v] + bzz);
          float nn = tanhf_(aNX[mi][v] + bin + rr * (aNH[mi][v] + bhn));
          float h = (1.f - zz) * nn + zz * hreg[mi][v];
          hreg[mi][v] = h;
          int row = R + mi * 16 + fq4 * 4 + v;
          hn[(kc * 128 + row) * 8 + sub] = f2bf(h);
        }
    }
    arrive(t + 2);
  }

  if (isFC) {
    wait_rel(75);
    fcdo(hb(0), 24, false);
  }
}

extern "C" void kernel_launch(void* const* d_in, const int* in_sizes, int n_in,
                              void* d_out, int out_size, void* d_ws, size_t ws_size,
                              hipStream_t stream) {
  const float* enc  = (const float*)d_in[0];
  const float* dec  = (const float*)d_in[1];
  const float* Wih  = (const float*)d_in[2];
  const float* Whh  = (const float*)d_in[3];
  const float* b_ih = (const float*)d_in[4];
  const float* b_hh = (const float*)d_in[5];
  const float* fcw  = (const float*)d_in[6];
  const float* fcb  = (const float*)d_in[7];
  float* out = (float*)d_out;

  char* ws = (char*)d_ws;
  unsigned* cnt  = (unsigned*)ws; ws += 65536;
  ushort_t* xg   = (ushort_t*)ws; ws += (size_t)8 * 49 * 8192 * 2;   // 6.42 MB
  ushort_t* hA   = (ushort_t*)ws; ws += (size_t)8 * 2 * 131072 * 2;  // 4 MB
  ushort_t* innA = (ushort_t*)ws; ws += (size_t)8 * 2 * 8192 * 2;    // 256 KB
  ushort_t* nG   = (ushort_t*)ws; ws += (size_t)8 * 32 * 32768 * 2;  // 16 MB
  ushort_t* fcG  = (ushort_t*)ws; ws += (size_t)8 * 65536 * 2;       // 1 MB

  (void)hipMemsetAsync(cnt, 0, 65536, stream);
  seq2seq_xcd<<<256, 512, 0, stream>>>(
      enc, dec, Wih, Whh, b_ih, b_hh, fcw, fcb, out,
      xg, hA, innA, nG, fcG, cnt);
}

// Round 8
// 1143.022 us; speedup vs baseline: 2.0694x; 2.0694x over previous
//
#include <hip/hip_runtime.h>

// Round 8: r6 revert + targeted fixes. XCD-local persistent GRU.
// 8 groups (physical XCDs via HW_REG_XCC_ID) x 32 blocks x 512 thr.
// K-split waves (4 row-groups x 2 K-halves, 12 MFMA/kt), conflict-free
// 2-round kreduce, depth-8 A prefetch, wave-4 distributed decoder FC.

typedef unsigned short ushort_t;
typedef __bf16 bf16x8 __attribute__((ext_vector_type(8)));
typedef float f32x4 __attribute__((ext_vector_type(4)));
typedef unsigned int u32x4 __attribute__((ext_vector_type(4)));

#define MFMA(a, b, c) __builtin_amdgcn_mfma_f32_16x16x32_bf16(a, b, c, 0, 0, 0)
#define AL(p) __hip_atomic_load(p, __ATOMIC_RELAXED, __HIP_MEMORY_SCOPE_AGENT)
#define AS(p, v) __hip_atomic_store(p, v, __ATOMIC_RELAXED, __HIP_MEMORY_SCOPE_AGENT)

static __device__ __forceinline__ ushort_t f2bf(float f) {
  union { float f; unsigned u; } x; x.f = f;
  unsigned r = x.u + 0x7fffu + ((x.u >> 16) & 1u);
  return (ushort_t)(r >> 16);
}
static __device__ __forceinline__ float sigmf(float x) { return 1.f / (1.f + __expf(-x)); }
static __device__ __forceinline__ float tanhf_(float x) { return 1.f - 2.f / (__expf(2.f * x) + 1.f); }

static __device__ __forceinline__ __amdgpu_buffer_rsrc_t mkrsrc(const void* p) {
  return __builtin_amdgcn_make_buffer_rsrc(const_cast<void*>(p), (short)0, -1, 0x00020000);
}
// aux=1 -> sc0: bypass vL1, read XCD-local L2 (cross-block coherent).
#if __has_builtin(__builtin_amdgcn_raw_buffer_load_b128)
static __device__ __forceinline__ bf16x8 ldb(__amdgpu_buffer_rsrc_t r, int voff) {
  u32x4 v = __builtin_amdgcn_raw_buffer_load_b128(r, voff, 0, 1);
  union { u32x4 u; bf16x8 b; } x; x.u = v; return x.b;
}
#else
static __device__ __forceinline__ bf16x8 ldb(__amdgpu_buffer_rsrc_t r, int voff) {
  union { unsigned u[4]; bf16x8 b; } x;
  x.u[0] = __builtin_amdgcn_raw_buffer_load_b32(r, voff, 0, 1);
  x.u[1] = __builtin_amdgcn_raw_buffer_load_b32(r, voff + 4, 0, 1);
  x.u[2] = __builtin_amdgcn_raw_buffer_load_b32(r, voff + 8, 0, 1);
  x.u[3] = __builtin_amdgcn_raw_buffer_load_b32(r, voff + 12, 0, 1);
  return x.b;
}
#endif

__global__ __launch_bounds__(512, 2)
void seq2seq_xcd(const float* __restrict__ enc, const float* __restrict__ dec,
                 const float* __restrict__ Wih, const float* __restrict__ Whh,
                 const float* __restrict__ b_ih, const float* __restrict__ b_hh,
                 const float* __restrict__ fcw, const float* __restrict__ fcb,
                 float* __restrict__ outp,
                 ushort_t* __restrict__ xg, ushort_t* __restrict__ hA,
                 ushort_t* __restrict__ innA, ushort_t* __restrict__ nG,
                 ushort_t* __restrict__ wiG, ushort_t* __restrict__ fcG,
                 unsigned* cnt) {
  __shared__ ushort_t WrzL[65536];  // [kt32][gate2(r,z)][jf2][ln64][8]  128 KB
  __shared__ float scr[6144];       // kreduce: [reg6][src4][lane64][4f]  24 KB
  __shared__ unsigned sgs;

  const int tid = threadIdx.x;
  const int w = tid >> 6, l = tid & 63;
  const int fr = l & 15, fq4 = l >> 4;

  // ---- claim XCD-local slot ----
  if (tid == 0) {
    unsigned x;
    asm volatile("s_getreg_b32 %0, hwreg(HW_REG_XCC_ID, 0, 8)" : "=s"(x));
    x &= 7u;
    unsigned s = atomicAdd(&cnt[x * 64], 1u);
    sgs = (x << 8) | s;
  }
  __syncthreads();
  const int g = sgs >> 8, slot = sgs & 255;

  unsigned* arrp = cnt + (8 + g) * 64;
  unsigned* relp = cnt + (16 + g * 4 + (slot & 3)) * 64;
  unsigned* relw = cnt + (16 + g * 4) * 64;
  auto fcpp = [&](int td) { return cnt + (48 + g * 25 + td) * 64; };

  ushort_t* hbase = hA + (size_t)g * 262144;
  auto hb = [&](int i) { return hbase + (size_t)i * 131072; };
  ushort_t* xgg = xg + (size_t)g * 49 * 8192;
  auto inng = [&](int i) { return innA + (size_t)(g * 2 + i) * 8192; };
  ushort_t* nGp = nG + (size_t)(g * 32 + slot) * 32768;
  ushort_t* wiGp = wiG + (size_t)(g * 32 + slot) * 8192;
  ushort_t* fcGg = fcG + (size_t)g * 65536;

  // ---- init: coalesced Whh -> WrzL (LDS) and nG (global), frag order ----
  {
    const int q = tid & 127, cc = tid >> 7;
    const int kt = q >> 2, lnp = (q & 3) * 16;
#pragma unroll
    for (int p = cc; p < 64; p += 4) {  // gates r,z
      int gt = p >> 5, c = p & 31;
      const float* src = Whh + (size_t)(gt * 1024 + slot * 32 + c) * 1024 + q * 8;
      ushort_t* dst = WrzL + kt * 2048 + gt * 1024 + (c >> 4) * 512 + ((c & 15) + lnp) * 8;
#pragma unroll
      for (int j = 0; j < 8; ++j) dst[j] = f2bf(src[j]);
    }
#pragma unroll
    for (int p = cc; p < 32; p += 4) {  // n-gate -> block-private global
      const float* src = Whh + (size_t)(2048 + slot * 32 + p) * 1024 + q * 8;
      ushort_t* dst = nGp + kt * 1024 + (p >> 4) * 512 + ((p & 15) + lnp) * 8;
#pragma unroll
      for (int j = 0; j < 8; ++j) dst[j] = f2bf(src[j]);
    }
  }
  for (int i = tid; i < 6144; i += 512) {  // wiG [kt2][gt3][jf2][ln64][8]
    int j = i & 7, ln = (i >> 3) & 63, jf = (i >> 9) & 1, rem = i >> 10;
    int gt = rem % 3, kt = rem / 3;
    int col = gt * 1024 + slot * 32 + jf * 16 + (ln & 15);
    int k = kt * 32 + (ln >> 4) * 8 + j;
    wiGp[i] = (k < 55) ? f2bf(Wih[(size_t)col * 55 + k]) : (ushort_t)0;
  }
#pragma unroll
  for (int rep = 0; rep < 2; ++rep) {  // x_enc: t = slot, slot+32
    int t = slot + rep * 32;
    if (t < 49) {
      ushort_t* xp = xgg + (size_t)t * 8192;
      for (int i = tid; i < 8192; i += 512) {
        int sub = i & 7, row = (i >> 3) & 127, kc = i >> 10;
        int c = kc * 8 + sub;
        xp[i] = (c < 55) ? f2bf(enc[((size_t)(g * 128 + row) * 50 + t) * 55 + c]) : (ushort_t)0;
      }
    }
  }
  if (slot < 4) {  // inn(0) = dec[:,0,:]
    ushort_t* ip = inng(0);
    for (int i = slot * 2048 + tid; i < (slot + 1) * 2048; i += 512) {
      int sub = i & 7, row = (i >> 3) & 127, kc = i >> 10;
      int c = kc * 8 + sub;
      ip[i] = (c < 55) ? f2bf(dec[(size_t)(g * 128 + row) * 1375 + c]) : (ushort_t)0;
    }
  }
  if (slot >= 24) {  // fcG [kt32][jf4][ln64][8], group-shared
    for (int i = (slot - 24) * 8192 + tid; i < (slot - 23) * 8192; i += 512) {
      int j = i & 7, ln = (i >> 3) & 63, jf = (i >> 9) & 3, kt = i >> 11;
      int c = jf * 16 + (ln & 15);
      int k = kt * 32 + (ln >> 4) * 8 + j;
      fcGg[i] = (c < 55) ? f2bf(fcw[(size_t)c * 1024 + k]) : (ushort_t)0;
    }
  }

  // ---- per-thread constants ----
  float brz[2], bzz[2], bin[2], bhn[2];
#pragma unroll
  for (int jf = 0; jf < 2; ++jf) {
    int col = slot * 32 + jf * 16 + fr;
    brz[jf] = b_ih[col] + b_hh[col];
    bzz[jf] = b_ih[1024 + col] + b_hh[1024 + col];
    bin[jf] = b_ih[2048 + col];
    bhn[jf] = b_hh[2048 + col];
  }
  // FC tile for this block: rows rT*16.., cols cT*16.. (wave 4 computes it)
  const int rT = slot & 7, cT = slot >> 3;
  const int colF = cT * 16 + fr;
  float fcbF = 0.f, inp[4] = {0.f, 0.f, 0.f, 0.f};
  if (w == 4) {
    fcbF = (colF < 55) ? fcb[colF] : 0.f;
#pragma unroll
    for (int v = 0; v < 4; ++v)
      inp[v] = (colF < 55) ? dec[(size_t)(g * 128 + rT * 16 + fq4 * 4 + v) * 1375 + colF] : 0.f;
  }
  f32x4 hreg[4];  // waves 0-3: [mi*2+jf]
#pragma unroll
  for (int i = 0; i < 4; ++i) hreg[i] = (f32x4){0.f, 0.f, 0.f, 0.f};

  // ---- barrier (r6-proven master/slave, no fences) ----
  auto arrive = [&](unsigned k) {
    __syncthreads();  // drains vmcnt: h stores complete at shared L2
    if (tid == 0) {
      if (slot == 0) {
        while (AL(arrp) < 31u * k) __builtin_amdgcn_s_sleep(1);
#pragma unroll
        for (int s = 0; s < 4; ++s) AS(relw + s * 64, k);
      } else {
        atomicAdd(arrp, 1u);
      }
    }
  };
  auto wait_rel = [&](unsigned k) {
    __syncthreads();
    if (tid == 0) {
      while (AL(relp) < k) __builtin_amdgcn_s_sleep(1);
    }
    __syncthreads();
  };
  auto fc_wait = [&](int td) {
    __syncthreads();
    if (tid == 0) {
      while (AL(fcpp(td)) < 32u) __builtin_amdgcn_s_sleep(1);
    }
    __syncthreads();
  };

  f32x4 av[12], nx[4];  // aR: av[0..3], aZ: av[4..7], aNH: av[8..11]

  auto xpart = [&](const ushort_t* xp) {  // waves 0-3, full K=64
    __amdgpu_buffer_rsrc_t rx = mkrsrc(xp);
    const int R = w * 32;
#pragma unroll
    for (int kt = 0; kt < 2; ++kt) {
      bf16x8 a0 = ldb(rx, ((kt * 4 + fq4) * 128 + R + fr) * 16);
      bf16x8 a1 = ldb(rx, ((kt * 4 + fq4) * 128 + R + 16 + fr) * 16);
      const ushort_t* bl = wiGp + kt * 3072 + l * 8;
#pragma unroll
      for (int jf = 0; jf < 2; ++jf) {
        bf16x8 br = *(const bf16x8*)(bl + jf * 512);
        bf16x8 bz = *(const bf16x8*)(bl + 1024 + jf * 512);
        bf16x8 bn = *(const bf16x8*)(bl + 2048 + jf * 512);
        av[jf] = MFMA(a0, br, av[jf]);
        av[2 + jf] = MFMA(a1, br, av[2 + jf]);
        av[4 + jf] = MFMA(a0, bz, av[4 + jf]);
        av[6 + jf] = MFMA(a1, bz, av[6 + jf]);
        nx[jf] = MFMA(a0, bn, nx[jf]);
        nx[2 + jf] = MFMA(a1, bn, nx[2 + jf]);
      }
    }
  };

  auto hpart = [&](const ushort_t* hbp) {  // all waves; K-split halves, depth-8
    __amdgpu_buffer_rsrc_t rb = mkrsrc(hbp);
    const int kh = w >> 2, R = (w & 3) * 32;
    bf16x8 A0[8], A1[8];
#pragma unroll
    for (int i = 0; i < 8; ++i) {
      int kt = kh * 16 + i;
      A0[i] = ldb(rb, ((kt * 4 + fq4) * 128 + R + fr) * 16);
      A1[i] = ldb(rb, ((kt * 4 + fq4) * 128 + R + 16 + fr) * 16);
    }
#pragma unroll
    for (int i = 0; i < 16; ++i) {
      int kt = kh * 16 + i;
      bf16x8 a0 = A0[i & 7], a1 = A1[i & 7];
      if (i < 8) {
        int kp = kt + 8;
        A0[i & 7] = ldb(rb, ((kp * 4 + fq4) * 128 + R + fr) * 16);
        A1[i & 7] = ldb(rb, ((kp * 4 + fq4) * 128 + R + 16 + fr) * 16);
      }
      const ushort_t* bl = WrzL + kt * 2048 + l * 8;
      const ushort_t* np = nGp + kt * 1024 + l * 8;
#pragma unroll
      for (int jf = 0; jf < 2; ++jf) {
        bf16x8 br = *(const bf16x8*)(bl + jf * 512);
        bf16x8 bz = *(const bf16x8*)(bl + 1024 + jf * 512);
        bf16x8 bn = *(const bf16x8*)(np + jf * 512);
        av[jf] = MFMA(a0, br, av[jf]);
        av[2 + jf] = MFMA(a1, br, av[2 + jf]);
        av[4 + jf] = MFMA(a0, bz, av[4 + jf]);
        av[6 + jf] = MFMA(a1, bz, av[6 + jf]);
        av[8 + jf] = MFMA(a0, bn, av[8 + jf]);
        av[10 + jf] = MFMA(a1, bn, av[10 + jf]);
      }
    }
  };

  // kreduce: 2 rounds x 6 f32x4, lane-contiguous 16B planes (conflict-free)
  auto kreduce = [&]() {
#pragma unroll
    for (int rd = 0; rd < 2; ++rd) {
      if (w >= 4) {
#pragma unroll
        for (int j = 0; j < 6; ++j)
          *(f32x4*)(scr + ((j * 4 + (w - 4)) * 64 + l) * 4) = av[rd * 6 + j];
      }
      __syncthreads();
      if (w < 4) {
#pragma unroll
        for (int j = 0; j < 6; ++j)
          av[rd * 6 + j] += *(const f32x4*)(scr + ((j * 4 + w) * 64 + l) * 4);
      }
      __syncthreads();
    }
  };

  // Decoder FC tile (wave 4 only): out(td) = inp + h@fc^T + fcb
  auto fcdo = [&](const ushort_t* hbp, int td, bool wr) {
    __amdgpu_buffer_rsrc_t rb = mkrsrc(hbp);
    const int rowb = (rT * 16 + fr) * 16;
    f32x4 fa = (f32x4){0.f, 0.f, 0.f, 0.f};
    bf16x8 Af[4];
#pragma unroll
    for (int i = 0; i < 4; ++i) Af[i] = ldb(rb, (i * 4 + fq4) * 2048 + rowb);
#pragma unroll
    for (int kt = 0; kt < 32; ++kt) {
      bf16x8 a = Af[kt & 3];
      if (kt < 28) Af[kt & 3] = ldb(rb, ((kt + 4) * 4 + fq4) * 2048 + rowb);
      fa = MFMA(a, *(const bf16x8*)(fcGg + kt * 2048 + cT * 512 + l * 8), fa);
    }
    const int kq = colF >> 3, sub = colF & 7;
    ushort_t* innW = inng((td + 1) & 1);
#pragma unroll
    for (int v = 0; v < 4; ++v) {
      int row = rT * 16 + fq4 * 4 + v;
      float o = fa[v] + inp[v] + fcbF;
      inp[v] = o;
      if (wr) innW[(kq * 128 + row) * 8 + sub] = f2bf(o);
      if (colF < 55) outp[(size_t)(g * 128 + row) * 1375 + td * 55 + colF] = o;
    }
    asm volatile("s_waitcnt vmcnt(0)");
    if (wr && l == 0) atomicAdd(fcpp(td), 1u);
  };

  arrive(1);
  wait_rel(1);

  for (int t = 0; t < 74; ++t) {
#pragma unroll
    for (int i = 0; i < 12; ++i) av[i] = (f32x4){0.f, 0.f, 0.f, 0.f};
#pragma unroll
    for (int i = 0; i < 4; ++i) nx[i] = (f32x4){0.f, 0.f, 0.f, 0.f};

    if (t <= 49 && w < 4) xpart(t <= 48 ? xgg + (size_t)t * 8192 : inng(0));
    if (t > 0) wait_rel(t + 1);
    if (t >= 50 && w == 4) fcdo(hb(t & 1), t - 50, true);
    if (t > 0) hpart(hb(t & 1));
    if (t >= 50) {
      fc_wait(t - 50);
      if (w < 4) xpart(inng((t - 49) & 1));
    }
    kreduce();
    if (w < 4) {  // epilogue: gates + fp32 carry + publish bf16 h(t+1)
      ushort_t* hn = hb((t + 1) & 1);
#pragma unroll
      for (int mi = 0; mi < 2; ++mi)
#pragma unroll
        for (int jf = 0; jf < 2; ++jf) {
          f32x4 R_ = av[mi * 2 + jf], Z_ = av[4 + mi * 2 + jf];
          f32x4 NH = av[8 + mi * 2 + jf], NX = nx[mi * 2 + jf];
          const int kq = slot * 4 + jf * 2 + (fr >> 3), sub = fr & 7;
#pragma unroll
          for (int v = 0; v < 4; ++v) {
            float rr = sigmf(R_[v] + brz[jf]);
            float zz = sigmf(Z_[v] + bzz[jf]);
            float nn = tanhf_(NX[v] + bin[jf] + rr * (NH[v] + bhn[jf]));
            float h = (1.f - zz) * nn + zz * hreg[mi * 2 + jf][v];
            hreg[mi * 2 + jf][v] = h;
            int row = w * 32 + mi * 16 + fq4 * 4 + v;
            hn[(kq * 128 + row) * 8 + sub] = f2bf(h);
          }
        }
    }
    arrive(t + 2);
  }

  wait_rel(75);
  if (w == 4) fcdo(hb(0), 24, false);
}

extern "C" void kernel_launch(void* const* d_in, const int* in_sizes, int n_in,
                              void* d_out, int out_size, void* d_ws, size_t ws_size,
                              hipStream_t stream) {
  const float* enc  = (const float*)d_in[0];
  const float* dec  = (const float*)d_in[1];
  const float* Wih  = (const float*)d_in[2];
  const float* Whh  = (const float*)d_in[3];
  const float* b_ih = (const float*)d_in[4];
  const float* b_hh = (const float*)d_in[5];
  const float* fcw  = (const float*)d_in[6];
  const float* fcb  = (const float*)d_in[7];
  float* out = (float*)d_out;

  char* ws = (char*)d_ws;
  unsigned* cnt  = (unsigned*)ws; ws += 65536;
  ushort_t* xg   = (ushort_t*)ws; ws += (size_t)8 * 49 * 8192 * 2;   // 6.42 MB
  ushort_t* hA   = (ushort_t*)ws; ws += (size_t)8 * 2 * 131072 * 2;  // 4 MB
  ushort_t* innA = (ushort_t*)ws; ws += (size_t)8 * 2 * 8192 * 2;    // 256 KB
  ushort_t* nG   = (ushort_t*)ws; ws += (size_t)8 * 32 * 32768 * 2;  // 16 MB
  ushort_t* wiG  = (ushort_t*)ws; ws += (size_t)8 * 32 * 8192 * 2;   // 4 MB
  ushort_t* fcG  = (ushort_t*)ws; ws += (size_t)8 * 65536 * 2;       // 1 MB

  (void)hipMemsetAsync(cnt, 0, 65536, stream);
  seq2seq_xcd<<<256, 512, 0, stream>>>(
      enc, dec, Wih, Whh, b_ih, b_hh, fcw, fcb, out,
      xg, hA, innA, nG, wiG, fcG, cnt);
}